// Round 8
// baseline (210.739 us; speedup 1.0000x reference)
//
#include <hip/hip_runtime.h>
#include <math.h>

#define HH 1024
#define WW 2048
#define HW (HH*WW)
#define KC 32
#define CAP 65536
#define SENT 0xFFFFFFFFu
#define BIAS 16777216.0f  /* 2^24 */

typedef unsigned long long u64;

struct Scratch {              // hist first: aligned
  unsigned hist[2048];
  unsigned done0, done1, done2;
  int ncand, cnt, kRemain, nvalid;
  unsigned prefix;
  float scale;
  float ck[KC], m2cy[KC], m2cx[KC];
};

// 256-thread parallel k-th-bucket selection over sc->hist (agent-coherent reads)
__device__ __forceinline__ unsigned agent_load(const unsigned* p){
  return __hip_atomic_load(p, __ATOMIC_RELAXED, __HIP_MEMORY_SCOPE_AGENT);
}
__device__ __forceinline__ void agent_store(unsigned* p, unsigned v){
  __hip_atomic_store(p, v, __ATOMIC_RELAXED, __HIP_MEMORY_SCOPE_AGENT);
}

template<int PASS>
__device__ void do_pick(Scratch* sc, const float* rch, unsigned* wsum){
  int t = threadIdx.x;
  unsigned v[8];
  #pragma unroll
  for (int j=0;j<8;j++) v[j] = agent_load(&sc->hist[t*8+j]);
  unsigned s = 0;
  #pragma unroll
  for (int j=0;j<8;j++) s += v[j];
  unsigned incl = s;
  #pragma unroll
  for (int d=1; d<64; d<<=1){ unsigned o = __shfl_up(incl, d); if ((t&63) >= d) incl += o; }
  unsigned excl = incl - s;
  if ((t&63)==63) wsum[t>>6] = incl;
  __syncthreads();
  unsigned woff=0, total=0;
  #pragma unroll
  for (int w=0;w<4;w++){ unsigned xw=wsum[w]; if (w < (t>>6)) woff += xw; total += xw; }
  unsigned pre = woff + excl;
  int k;
  if (PASS==0){
    k = (total>0) ? (int)((total-1)>>1) : 0;
  } else {
    k = sc->kRemain;
  }
  if (total>0 && (unsigned)k >= pre && (unsigned)k < pre + s){
    unsigned kr = (unsigned)k - pre;
    int b_ = 0;
    #pragma unroll
    for (int j=0;j<8;j++){
      if (kr < v[j]){ b_ = t*8+j; break; }
      kr -= v[j];
    }
    sc->kRemain = (int)kr;
    if (PASS==0)      sc->prefix = (unsigned)b_;
    else if (PASS==1) sc->prefix = (sc->prefix << 11) | (unsigned)b_;
    else {
      unsigned key = (sc->prefix << 10) | (unsigned)b_;
      sc->scale = rch[0] / __uint_as_float(key);
    }
  }
  if (PASS==2 && t==0 && total==0) sc->scale = 0.0f;
  if (PASS < 2){
    __syncthreads();
    #pragma unroll
    for (int j=0;j<8;j++) agent_store(&sc->hist[t*8+j], 0u);
  }
}

__global__ __launch_bounds__(1024) void k_init(Scratch* sc){
  int t = threadIdx.x;
  ((uint2*)sc->hist)[t] = make_uint2(0u,0u);
  if (t==0){ sc->ncand=0; sc->cnt=0; sc->done0=0u; sc->done1=0u; sc->done2=0u; }
}

// pure streaming: heat-candidate collect + surface-normal heights + ground compact
// 4 px/thread, grid 2048, NO LDS, NO barriers
__global__ __launch_bounds__(256) void kA(const float* __restrict__ heat,
    const int* __restrict__ sem, const float* __restrict__ depth,
    const float* __restrict__ invK, u64* __restrict__ cand,
    unsigned* __restrict__ cheight, Scratch* __restrict__ sc){
  int t = threadIdx.x;
  int i4 = blockIdx.x*256 + t;
  int p = i4<<2;
  int y = p>>11, x = p&2047;
  int row = y<<11;

  float4 hq = ((const float4*)heat)[i4];
  int4   s4 = ((const int4*)sem)[i4];
  float4 dc = ((const float4*)depth)[i4];
  float  dl = depth[row + (x>0 ? x-1 : 0)];
  float  dr = depth[row + (x+4<WW ? x+4 : WW-1)];
  int rowu = (y>0)?    row-WW : row;
  int rowd = (y<HH-1)? row+WW : row;
  float4 du = ((const float4*)(depth + rowu))[x>>2];
  float4 dd = ((const float4*)(depth + rowd))[x>>2];
  float ik0=invK[0],ik1=invK[1],ik2=invK[2];
  float ik3=invK[3],ik4=invK[4],ik5=invK[5];
  float ik6=invK[6],ik7=invK[7],ik8=invK[8];

  float hv[4] = {hq.x,hq.y,hq.z,hq.w};
  int   sv[4] = {s4.x,s4.y,s4.z,s4.w};
  float dcv[4]= {dc.x,dc.y,dc.z,dc.w};
  float duv[4]= {du.x,du.y,du.z,du.w};
  float ddv[4]= {dd.x,dd.y,dd.z,dd.w};

  // --- candidate collect: wave-aggregated compaction ---
  unsigned npos = 0;
  #pragma unroll
  for (int j=0;j<4;j++) npos += (hv[j] > 0.0f) ? 1u : 0u;
  {
    unsigned incl = npos;
    #pragma unroll
    for (int d=1; d<64; d<<=1){ unsigned o = __shfl_up(incl, d); if ((t&63) >= d) incl += o; }
    unsigned wtot = __shfl(incl, 63);
    if (wtot){
      unsigned base = 0;
      if ((t&63)==63) base = (unsigned)atomicAdd(&sc->ncand, (int)wtot);
      base = __shfl(base, 63);
      unsigned slot = base + incl - npos;
      #pragma unroll
      for (int j=0;j<4;j++){
        if (hv[j] > 0.0f){
          if (slot < CAP)
            cand[slot] = ((u64)__float_as_uint(hv[j])<<32) | (u64)(unsigned)(~(unsigned)(p+j));
          slot++;
        }
      }
    }
  }

  // --- surface-normal heights ---
  float fy = (float)y;
  float a0=ik1*fy+ik2, a1=ik4*fy+ik5, a2=ik7*fy+ik8;
  float fyu=(y>0)?    fy-1.0f : fy;
  float fyd=(y<HH-1)? fy+1.0f : fy;
  float uu0=ik1*fyu+ik2, uu1=ik4*fyu+ik5, uu2=ik7*fyu+ik8;
  float ww0=ik1*fyd+ik2, ww1=ik4*fyd+ik5, ww2=ik7*fyd+ik8;
  float dxmv[4] = {dl, dcv[0], dcv[1], dcv[2]};
  float dxpv[4] = {dcv[1], dcv[2], dcv[3], dr};
  float h[4];
  #pragma unroll
  for (int j=0;j<4;j++){
    float fx  = (float)(x+j);
    float fxm = (x+j>0)?    fx-1.0f : fx;
    float fxp = (x+j<WW-1)? fx+1.0f : fx;
    float pc0=(ik0*fx +a0)*dcv[j],  pc1=(ik3*fx +a1)*dcv[j],  pc2=(ik6*fx +a2)*dcv[j];
    float pm0=(ik0*fxm+a0)*dxmv[j], pm1=(ik3*fxm+a1)*dxmv[j], pm2=(ik6*fxm+a2)*dxmv[j];
    float pp0=(ik0*fxp+a0)*dxpv[j], pp1=(ik3*fxp+a1)*dxpv[j], pp2=(ik6*fxp+a2)*dxpv[j];
    float pu0=(ik0*fx+uu0)*duv[j],  pu1=(ik3*fx+uu1)*duv[j],  pu2=(ik6*fx+uu2)*duv[j];
    float pd0=(ik0*fx+ww0)*ddv[j],  pd1=(ik3*fx+ww1)*ddv[j],  pd2=(ik6*fx+ww2)*ddv[j];
    float vx0=pp0-pm0, vx1=pp1-pm1, vx2=pp2-pm2;
    float vy0=pd0-pu0, vy1=pd1-pu1, vy2=pd2-pu2;
    float n0=vx1*vy2-vx2*vy1, n1=vx2*vy0-vx0*vy2, n2=vx0*vy1-vx1*vy0;
    float nn = sqrtf(n0*n0+n1*n1+n2*n2) + 1e-8f;
    h[j] = fabsf(pc0*n0+pc1*n1+pc2*n2) / nn;
  }

  // --- ground-height compact: wave-aggregated ---
  unsigned ng = 0;
  #pragma unroll
  for (int j=0;j<4;j++) ng += (sv[j]==0) ? 1u : 0u;
  {
    unsigned incl = ng;
    #pragma unroll
    for (int d=1; d<64; d<<=1){ unsigned o = __shfl_up(incl, d); if ((t&63) >= d) incl += o; }
    unsigned wtot = __shfl(incl, 63);
    if (wtot){
      unsigned base = 0;
      if ((t&63)==63) base = (unsigned)atomicAdd(&sc->cnt, (int)wtot);
      base = __shfl(base, 63);
      unsigned slot = base + incl - ng;
      #pragma unroll
      for (int j=0;j<4;j++){
        if (sv[j]==0){ cheight[slot] = __float_as_uint(h[j]); slot++; }
      }
    }
  }
}

// 1024 threads = 16 waves: per-wave register top-32 + 16-way merge
__global__ __launch_bounds__(1024) void k_select(const u64* __restrict__ cand, Scratch* sc){
  __shared__ u64 loc[16*KC];
  int t = threadIdx.x;
  int lane = t & 63;
  int w = t >> 6;
  int n = sc->ncand; if (n > CAP) n = CAP;

  if (t < 16*KC) loc[t] = 0ULL;
  __syncthreads();

  int chunk = (n + 15) >> 4;
  int start = w * chunk;
  int end   = min(n, start + chunk);

  u64 rv[8];
  #pragma unroll
  for (int i=0;i<8;i++){
    int idx = start + lane + (i<<6);
    rv[i] = (idx < end) ? cand[idx] : 0ULL;
  }
  bool over = (end - start) > 512;

  u64 prev = ~0ULL;
  for (int r=0;r<KC;r++){
    u64 best = 0ULL;
    #pragma unroll
    for (int i=0;i<8;i++){ u64 key = rv[i]; if (key < prev && key > best) best = key; }
    if (over){
      for (int idx = start + 512 + lane; idx < end; idx += 64){
        u64 key = cand[idx]; if (key < prev && key > best) best = key;
      }
    }
    #pragma unroll
    for (int m=32;m>=1;m>>=1){ u64 o = __shfl_xor(best, m); if (o > best) best = o; }
    if (best == 0ULL) break;
    if (lane == 0) loc[w*KC + r] = best;
    prev = best;
  }
  __syncthreads();

  if (w == 0){
    int ptr = lane * KC;
    int lim = ptr + KC;
    int k = 0;
    for (int r=0;r<KC;r++){
      u64 key = (lane < 16 && ptr < lim) ? loc[ptr] : 0ULL;
      u64 mx = key;
      #pragma unroll
      for (int m=32;m>=1;m>>=1){ u64 o = __shfl_xor(mx, m); if (o > mx) mx = o; }
      if (mx == 0ULL) break;
      u64 ball = __ballot(key == mx);
      int winner = __ffsll((long long)ball) - 1;
      if (lane == winner) ptr++;
      if (lane == 0){
        unsigned idx = ~(unsigned)(mx & 0xFFFFFFFFULL);
        float cy = (float)(idx >> 11), cx = (float)(idx & 2047u);
        sc->ck[r]   = cy*cy + cx*cx + BIAS;
        sc->m2cy[r] = -2.0f*cy;
        sc->m2cx[r] = -2.0f*cx;
      }
      k = r + 1;
    }
    if (lane == 0) sc->nvalid = k;
  }
}

// histogram over compact ground heights (L2-resident) + ticket-fused pick
template<int PASS>
__global__ __launch_bounds__(256) void k_h(const unsigned* __restrict__ ch,
    Scratch* __restrict__ sc, const float* __restrict__ rch){
  __shared__ unsigned hsh[2048];
  __shared__ unsigned wsum[4];
  __shared__ int lastf;
  int t = threadIdx.x;
  for (int j=t;j<2048;j+=256) hsh[j]=0u;
  __syncthreads();
  int n = sc->cnt;
  unsigned pref = sc->prefix;
  for (int i = blockIdx.x*256 + t; i < n; i += gridDim.x*256){
    unsigned key = ch[i];
    if (PASS==0)      atomicAdd(&hsh[key>>21], 1u);
    else if (PASS==1){ if ((key>>21) == pref) atomicAdd(&hsh[(key>>10)&2047u], 1u); }
    else             { if ((key>>10) == pref) atomicAdd(&hsh[key & 1023u], 1u); }
  }
  __syncthreads();
  for (int j=t;j<2048;j+=256){ unsigned v=hsh[j]; if (v) atomicAdd(&sc->hist[j], v); }
  __syncthreads();   // drains vmcnt: hist atomics complete before ticket
  if (t==0){
    unsigned* dp = (PASS==0)? &sc->done0 : (PASS==1)? &sc->done1 : &sc->done2;
    lastf = (atomicAdd(dp, 1u) == (unsigned)(gridDim.x-1)) ? 1 : 0;
  }
  __syncthreads();
  if (lastf) do_pick<PASS>(sc, rch, wsum);
}

// labels + scaled depth + cam_out; 4 px/thread, grid 2048
__global__ __launch_bounds__(256) void k_final(const int* __restrict__ sem,
    const float* __restrict__ off, const float* __restrict__ depth,
    const float* __restrict__ invK, const Scratch* __restrict__ sc,
    float* __restrict__ out){
  __shared__ float sck[KC], smy[KC], smx[KC];
  __shared__ int snv; __shared__ float ssc;
  int t = threadIdx.x;
  if (t < KC){ sck[t]=sc->ck[t]; smy[t]=sc->m2cy[t]; smx[t]=sc->m2cx[t]; }
  if (t == 0){ snv = sc->nvalid; ssc = sc->scale; }
  __syncthreads();

  int i4 = blockIdx.x*256 + t;
  int p = i4<<2;
  int y = p>>11, x = p&2047;
  int4   s4 = ((const int4*)sem)[i4];
  float4 oy = ((const float4*)off)[i4];
  float4 ox = ((const float4*)(off+HW))[i4];
  float4 dc = ((const float4*)depth)[i4];

  float ik0=invK[0],ik1=invK[1],ik2=invK[2];
  float ik3=invK[3],ik4=invK[4],ik5=invK[5];
  float ik6=invK[6],ik7=invK[7],ik8=invK[8];
  float fy = (float)y;
  float a0=ik1*fy+ik2, a1=ik4*fy+ik5, a2=ik7*fy+ik8;
  int nv = snv; float s = ssc;

  int   sv[4]  = {s4.x,s4.y,s4.z,s4.w};
  float oyv[4] = {oy.x,oy.y,oy.z,oy.w};
  float oxv[4] = {ox.x,ox.y,ox.z,ox.w};
  float dv[4]  = {dc.x,dc.y,dc.z,dc.w};

  float ys[4], xs[4]; unsigned ub[4];
  #pragma unroll
  for (int j=0;j<4;j++){
    ys[j] = fy + oyv[j]; xs[j] = (float)(x+j) + oxv[j]; ub[j] = SENT;
  }
  for (int k=0;k<nv;k++){
    float ckk=sck[k], my=smy[k], mx=smx[k];
    #pragma unroll
    for (int j=0;j<4;j++){
      float tt = fmaf(ys[j], my, ckk);
      tt = fmaf(xs[j], mx, tt);
      unsigned u = (__float_as_uint(tt) & ~31u) | (unsigned)k;
      ub[j] = u < ub[j] ? u : ub[j];
    }
  }
  float lab[4], depo[4];
  float4* cam = (float4*)(out + (size_t)2*HW);
  #pragma unroll
  for (int j=0;j<4;j++){
    int sj = sv[j];
    lab[j] = (sj >= 11 && nv > 0) ? (float)(sj*1000 + (int)(ub[j]&31u) + 1) : (float)sj;
    float fx = (float)(x+j);
    float ds = dv[j]*s;
    float p0=(ik0*fx+a0)*ds, p1=(ik3*fx+a1)*ds, p2=(ik6*fx+a2)*ds;
    bool filt = (lab[j]==10.0f) || (lab[j]==19.0f);
    depo[j] = filt ? 0.0f : ds;
    cam[p+j] = make_float4(p0, p1, p2, lab[j]);
  }
  ((float4*)out)[i4]      = make_float4(lab[0], lab[1], lab[2], lab[3]);
  ((float4*)(out+HW))[i4] = make_float4(depo[0], depo[1], depo[2], depo[3]);
}

extern "C" void kernel_launch(void* const* d_in, const int* in_sizes, int n_in,
                              void* d_out, int out_size, void* d_ws, size_t ws_size,
                              hipStream_t stream){
  const int*   sem   = (const int*)d_in[0];
  const float* heat  = (const float*)d_in[1];
  const float* off   = (const float*)d_in[2];
  const float* depth = (const float*)d_in[3];
  const float* invK  = (const float*)d_in[4];
  const float* rch   = (const float*)d_in[5];
  float* out = (float*)d_out;

  unsigned* cheight = (unsigned*)d_ws;                                   // HW*4 bytes cap
  u64* cand = (u64*)((char*)d_ws + (size_t)HW*4);                        // CAP*8 bytes
  Scratch* sc = (Scratch*)((char*)d_ws + (size_t)HW*4 + (size_t)CAP*8);

  const int grid4 = HW/4/256;   // 2048

  k_init<<<1, 1024, 0, stream>>>(sc);
  kA<<<grid4, 256, 0, stream>>>(heat, sem, depth, invK, cand, cheight, sc);
  k_select<<<1, 1024, 0, stream>>>(cand, sc);
  k_h<0><<<64, 256, 0, stream>>>(cheight, sc, rch);
  k_h<1><<<64, 256, 0, stream>>>(cheight, sc, rch);
  k_h<2><<<64, 256, 0, stream>>>(cheight, sc, rch);
  k_final<<<grid4, 256, 0, stream>>>(sem, off, depth, invK, sc, out);
}

// Round 9
// 120.140 us; speedup vs baseline: 1.7541x; 1.7541x over previous
//
#include <hip/hip_runtime.h>
#include <math.h>

#define HH 1024
#define WW 2048
#define HW (HH*WW)
#define KC 32
#define LCAP 6144
#define CREG 16          /* candidate slots per block (mean 1.4/block, P(>16)~1e-12) */
#define SENT 0xFFFFFFFFu
#define BIAS 16777216.0f /* 2^24 */

typedef unsigned long long u64;

struct Scratch {
  unsigned hist[2048];
  unsigned done0, done1, done2;
  int kRemain, nvalid;
  unsigned prefix;
  float scale;
  float ck[KC], m2cy[KC], m2cx[KC];
  unsigned ccnt[2048];   // candidates per kA-block
  unsigned cblk[2048];   // ground heights per kA-block
};

__device__ __forceinline__ unsigned agent_load(const unsigned* p){
  return __hip_atomic_load(p, __ATOMIC_RELAXED, __HIP_MEMORY_SCOPE_AGENT);
}
__device__ __forceinline__ void agent_store(unsigned* p, unsigned v){
  __hip_atomic_store(p, v, __ATOMIC_RELAXED, __HIP_MEMORY_SCOPE_AGENT);
}

// 256-thread parallel k-th-bucket selection over sc->hist
template<int PASS>
__device__ void do_pick(Scratch* sc, const float* rch, unsigned* wsum){
  int t = threadIdx.x;
  unsigned v[8];
  #pragma unroll
  for (int j=0;j<8;j++) v[j] = agent_load(&sc->hist[t*8+j]);
  unsigned s = 0;
  #pragma unroll
  for (int j=0;j<8;j++) s += v[j];
  unsigned incl = s;
  #pragma unroll
  for (int d=1; d<64; d<<=1){ unsigned o = __shfl_up(incl, d); if ((t&63) >= d) incl += o; }
  unsigned excl = incl - s;
  if ((t&63)==63) wsum[t>>6] = incl;
  __syncthreads();
  unsigned woff=0, total=0;
  #pragma unroll
  for (int w=0;w<4;w++){ unsigned xw=wsum[w]; if (w < (t>>6)) woff += xw; total += xw; }
  unsigned pre = woff + excl;
  int k;
  if (PASS==0) k = (total>0) ? (int)((total-1)>>1) : 0;
  else         k = sc->kRemain;
  if (total>0 && (unsigned)k >= pre && (unsigned)k < pre + s){
    unsigned kr = (unsigned)k - pre;
    int b_ = 0;
    #pragma unroll
    for (int j=0;j<8;j++){
      if (kr < v[j]){ b_ = t*8+j; break; }
      kr -= v[j];
    }
    sc->kRemain = (int)kr;
    if (PASS==0)      sc->prefix = (unsigned)b_;
    else if (PASS==1) sc->prefix = (sc->prefix << 11) | (unsigned)b_;
    else {
      unsigned key = (sc->prefix << 10) | (unsigned)b_;
      sc->scale = rch[0] / __uint_as_float(key);
    }
  }
  if (PASS==2 && t==0 && total==0) sc->scale = 0.0f;
  if (PASS < 2){
    __syncthreads();
    #pragma unroll
    for (int j=0;j<8;j++) agent_store(&sc->hist[t*8+j], 0u);
  }
}

__global__ __launch_bounds__(1024) void k_init(Scratch* sc){
  int t = threadIdx.x;
  ((uint2*)sc->hist)[t] = make_uint2(0u,0u);
  if (t==0){ sc->done0=0u; sc->done1=0u; sc->done2=0u; }
}

// streaming: candidate + ground compaction into per-block regions (NO global atomics)
// 4 px/thread, grid 2048, one barrier
__global__ __launch_bounds__(256) void kA(const float* __restrict__ heat,
    const int* __restrict__ sem, const float* __restrict__ depth,
    const float* __restrict__ invK, u64* __restrict__ cand,
    unsigned* __restrict__ cheight, Scratch* __restrict__ sc){
  __shared__ unsigned wc_c[4], wc_g[4];
  int t = threadIdx.x;
  int i4 = blockIdx.x*256 + t;
  int p = i4<<2;
  int y = p>>11, x = p&2047;
  int row = y<<11;

  float4 hq = ((const float4*)heat)[i4];
  int4   s4 = ((const int4*)sem)[i4];
  float4 dc = ((const float4*)depth)[i4];
  float  dl = depth[row + (x>0 ? x-1 : 0)];
  float  dr = depth[row + (x+4<WW ? x+4 : WW-1)];
  int rowu = (y>0)?    row-WW : row;
  int rowd = (y<HH-1)? row+WW : row;
  float4 du = ((const float4*)(depth + rowu))[x>>2];
  float4 dd = ((const float4*)(depth + rowd))[x>>2];
  float ik0=invK[0],ik1=invK[1],ik2=invK[2];
  float ik3=invK[3],ik4=invK[4],ik5=invK[5];
  float ik6=invK[6],ik7=invK[7],ik8=invK[8];

  float hv[4] = {hq.x,hq.y,hq.z,hq.w};
  int   sv[4] = {s4.x,s4.y,s4.z,s4.w};
  float dcv[4]= {dc.x,dc.y,dc.z,dc.w};
  float duv[4]= {du.x,du.y,du.z,du.w};
  float ddv[4]= {dd.x,dd.y,dd.z,dd.w};

  // wave-local counts + scans (no memory ops)
  unsigned npos = 0, ng = 0;
  #pragma unroll
  for (int j=0;j<4;j++){ npos += (hv[j] > 0.0f) ? 1u : 0u; ng += (sv[j]==0) ? 1u : 0u; }
  unsigned incc = npos, incg = ng;
  #pragma unroll
  for (int d=1; d<64; d<<=1){
    unsigned oc = __shfl_up(incc, d), og = __shfl_up(incg, d);
    if ((t&63) >= d){ incc += oc; incg += og; }
  }
  if ((t&63)==63){ wc_c[t>>6] = incc; wc_g[t>>6] = incg; }

  // --- surface-normal heights (overlaps LDS visibility) ---
  float fy = (float)y;
  float a0=ik1*fy+ik2, a1=ik4*fy+ik5, a2=ik7*fy+ik8;
  float fyu=(y>0)?    fy-1.0f : fy;
  float fyd=(y<HH-1)? fy+1.0f : fy;
  float uu0=ik1*fyu+ik2, uu1=ik4*fyu+ik5, uu2=ik7*fyu+ik8;
  float ww0=ik1*fyd+ik2, ww1=ik4*fyd+ik5, ww2=ik7*fyd+ik8;
  float dxmv[4] = {dl, dcv[0], dcv[1], dcv[2]};
  float dxpv[4] = {dcv[1], dcv[2], dcv[3], dr};
  float h[4];
  #pragma unroll
  for (int j=0;j<4;j++){
    float fx  = (float)(x+j);
    float fxm = (x+j>0)?    fx-1.0f : fx;
    float fxp = (x+j<WW-1)? fx+1.0f : fx;
    float pc0=(ik0*fx +a0)*dcv[j],  pc1=(ik3*fx +a1)*dcv[j],  pc2=(ik6*fx +a2)*dcv[j];
    float pm0=(ik0*fxm+a0)*dxmv[j], pm1=(ik3*fxm+a1)*dxmv[j], pm2=(ik6*fxm+a2)*dxmv[j];
    float pp0=(ik0*fxp+a0)*dxpv[j], pp1=(ik3*fxp+a1)*dxpv[j], pp2=(ik6*fxp+a2)*dxpv[j];
    float pu0=(ik0*fx+uu0)*duv[j],  pu1=(ik3*fx+uu1)*duv[j],  pu2=(ik6*fx+uu2)*duv[j];
    float pd0=(ik0*fx+ww0)*ddv[j],  pd1=(ik3*fx+ww1)*ddv[j],  pd2=(ik6*fx+ww2)*ddv[j];
    float vx0=pp0-pm0, vx1=pp1-pm1, vx2=pp2-pm2;
    float vy0=pd0-pu0, vy1=pd1-pu1, vy2=pd2-pu2;
    float n0=vx1*vy2-vx2*vy1, n1=vx2*vy0-vx0*vy2, n2=vx0*vy1-vx1*vy0;
    float nn = sqrtf(n0*n0+n1*n1+n2*n2) + 1e-8f;
    h[j] = fabsf(pc0*n0+pc1*n1+pc2*n2) / nn;
  }

  __syncthreads();
  unsigned cboff=0, gboff=0;
  int myw = t>>6;
  #pragma unroll
  for (int w=0;w<4;w++){
    if (w < myw){ cboff += wc_c[w]; gboff += wc_g[w]; }
  }
  // candidate writes (region of CREG per block)
  if (npos){
    unsigned cslot = cboff + incc - npos;
    u64* cb = cand + ((size_t)blockIdx.x * CREG);
    #pragma unroll
    for (int j=0;j<4;j++){
      if (hv[j] > 0.0f){
        if (cslot < CREG)
          cb[cslot] = ((u64)__float_as_uint(hv[j])<<32) | (u64)(unsigned)(~(unsigned)(p+j));
        cslot++;
      }
    }
  }
  // ground writes (region of 1024 per block)
  if (ng){
    unsigned gslot = ((unsigned)blockIdx.x<<10) + gboff + incg - ng;
    #pragma unroll
    for (int j=0;j<4;j++){
      if (sv[j]==0){ cheight[gslot++] = __float_as_uint(h[j]); }
    }
  }
  if (t==0){
    unsigned tc = wc_c[0]+wc_c[1]+wc_c[2]+wc_c[3];
    sc->ccnt[blockIdx.x] = (tc > CREG) ? CREG : tc;
    sc->cblk[blockIdx.x] = wc_g[0]+wc_g[1]+wc_g[2]+wc_g[3];
  }
}

// 1 block, 1024 thr: compact candidate regions into LDS, then 16-wave top-32 + merge
__global__ __launch_bounds__(1024) void k_select(const u64* __restrict__ cand, Scratch* sc){
  __shared__ u64 lcache[LCAP];
  __shared__ u64 loc[16*KC];
  __shared__ unsigned stot;
  int t = threadIdx.x;
  int lane = t & 63;
  int w = t >> 6;
  if (t==0) stot = 0u;
  if (t < 16*KC) loc[t] = 0ULL;
  __syncthreads();

  #pragma unroll
  for (int rep=0; rep<2; rep++){
    int r = t + rep*1024;
    unsigned c = sc->ccnt[r];
    if (c){
      unsigned b = atomicAdd(&stot, c);
      const u64* cb = cand + ((size_t)r * CREG);
      for (unsigned i=0;i<c;i++){
        unsigned pos = b+i;
        if (pos < LCAP) lcache[pos] = cb[i];
      }
    }
  }
  __syncthreads();
  int n = (int)stot; if (n > LCAP) n = LCAP;

  int chunk = (n + 15) >> 4;
  int start = w * chunk;
  int end   = min(n, start + chunk);
  u64 rv[8];
  #pragma unroll
  for (int i=0;i<8;i++){
    int idx = start + lane + (i<<6);
    rv[i] = (idx < end) ? lcache[idx] : 0ULL;
  }
  bool over = (end - start) > 512;

  u64 prev = ~0ULL;
  for (int r=0;r<KC;r++){
    u64 best = 0ULL;
    #pragma unroll
    for (int i=0;i<8;i++){ u64 key = rv[i]; if (key < prev && key > best) best = key; }
    if (over){
      for (int idx = start + 512 + lane; idx < end; idx += 64){
        u64 key = lcache[idx]; if (key < prev && key > best) best = key;
      }
    }
    #pragma unroll
    for (int m=32;m>=1;m>>=1){ u64 o = __shfl_xor(best, m); if (o > best) best = o; }
    if (best == 0ULL) break;
    if (lane == 0) loc[w*KC + r] = best;
    prev = best;
  }
  __syncthreads();

  if (w == 0){
    int ptr = lane * KC;
    int lim = ptr + KC;
    int k = 0;
    for (int r=0;r<KC;r++){
      u64 key = (lane < 16 && ptr < lim) ? loc[ptr] : 0ULL;
      u64 mx = key;
      #pragma unroll
      for (int m=32;m>=1;m>>=1){ u64 o = __shfl_xor(mx, m); if (o > mx) mx = o; }
      if (mx == 0ULL) break;
      u64 ball = __ballot(key == mx);
      int winner = __ffsll((long long)ball) - 1;
      if (lane == winner) ptr++;
      if (lane == 0){
        unsigned idx = ~(unsigned)(mx & 0xFFFFFFFFULL);
        float cy = (float)(idx >> 11), cx = (float)(idx & 2047u);
        sc->ck[r]   = cy*cy + cx*cx + BIAS;
        sc->m2cy[r] = -2.0f*cy;
        sc->m2cx[r] = -2.0f*cx;
      }
      k = r + 1;
    }
    if (lane == 0) sc->nvalid = k;
  }
}

// histogram over per-block ground regions + ticket-fused pick; grid 64
template<int PASS>
__global__ __launch_bounds__(256) void k_h(const unsigned* __restrict__ ch,
    Scratch* __restrict__ sc, const float* __restrict__ rch){
  __shared__ unsigned hsh[2048];
  __shared__ unsigned cnts[32];
  __shared__ unsigned wsum[4];
  __shared__ int lastf;
  int t = threadIdx.x;
  for (int j=t;j<2048;j+=256) hsh[j]=0u;
  int r0 = blockIdx.x * 32;
  if (t < 32) cnts[t] = sc->cblk[r0+t];
  __syncthreads();
  unsigned pref = sc->prefix;
  for (int r=0;r<32;r++){
    unsigned c = cnts[r];
    const unsigned* base = ch + ((size_t)(r0+r)<<10);
    for (unsigned i=t; i<c; i+=256){
      unsigned key = base[i];
      if (PASS==0)      atomicAdd(&hsh[key>>21], 1u);
      else if (PASS==1){ if ((key>>21) == pref) atomicAdd(&hsh[(key>>10)&2047u], 1u); }
      else             { if ((key>>10) == pref) atomicAdd(&hsh[key & 1023u], 1u); }
    }
  }
  __syncthreads();
  for (int j=t;j<2048;j+=256){ unsigned v=hsh[j]; if (v) atomicAdd(&sc->hist[j], v); }
  __syncthreads();   // drains vmcnt: hist atomics complete before ticket
  if (t==0){
    unsigned* dp = (PASS==0)? &sc->done0 : (PASS==1)? &sc->done1 : &sc->done2;
    lastf = (atomicAdd(dp, 1u) == (unsigned)(gridDim.x-1)) ? 1 : 0;
  }
  __syncthreads();
  if (lastf) do_pick<PASS>(sc, rch, wsum);
}

// labels + scaled depth + cam_out; 4 px/thread, grid 2048
__global__ __launch_bounds__(256) void k_final(const int* __restrict__ sem,
    const float* __restrict__ off, const float* __restrict__ depth,
    const float* __restrict__ invK, const Scratch* __restrict__ sc,
    float* __restrict__ out){
  __shared__ float sck[KC], smy[KC], smx[KC];
  __shared__ int snv; __shared__ float ssc;
  int t = threadIdx.x;
  if (t < KC){ sck[t]=sc->ck[t]; smy[t]=sc->m2cy[t]; smx[t]=sc->m2cx[t]; }
  if (t == 0){ snv = sc->nvalid; ssc = sc->scale; }
  __syncthreads();

  int i4 = blockIdx.x*256 + t;
  int p = i4<<2;
  int y = p>>11, x = p&2047;
  int4   s4 = ((const int4*)sem)[i4];
  float4 oy = ((const float4*)off)[i4];
  float4 ox = ((const float4*)(off+HW))[i4];
  float4 dc = ((const float4*)depth)[i4];

  float ik0=invK[0],ik1=invK[1],ik2=invK[2];
  float ik3=invK[3],ik4=invK[4],ik5=invK[5];
  float ik6=invK[6],ik7=invK[7],ik8=invK[8];
  float fy = (float)y;
  float a0=ik1*fy+ik2, a1=ik4*fy+ik5, a2=ik7*fy+ik8;
  int nv = snv; float s = ssc;

  int   sv[4]  = {s4.x,s4.y,s4.z,s4.w};
  float oyv[4] = {oy.x,oy.y,oy.z,oy.w};
  float oxv[4] = {ox.x,ox.y,ox.z,ox.w};
  float dv[4]  = {dc.x,dc.y,dc.z,dc.w};

  float ys[4], xs[4]; unsigned ub[4];
  #pragma unroll
  for (int j=0;j<4;j++){
    ys[j] = fy + oyv[j]; xs[j] = (float)(x+j) + oxv[j]; ub[j] = SENT;
  }
  for (int k=0;k<nv;k++){
    float ckk=sck[k], my=smy[k], mx=smx[k];
    #pragma unroll
    for (int j=0;j<4;j++){
      float tt = fmaf(ys[j], my, ckk);
      tt = fmaf(xs[j], mx, tt);
      unsigned u = (__float_as_uint(tt) & ~31u) | (unsigned)k;
      ub[j] = u < ub[j] ? u : ub[j];
    }
  }
  float lab[4], depo[4];
  float4* cam = (float4*)(out + (size_t)2*HW);
  #pragma unroll
  for (int j=0;j<4;j++){
    int sj = sv[j];
    lab[j] = (sj >= 11 && nv > 0) ? (float)(sj*1000 + (int)(ub[j]&31u) + 1) : (float)sj;
    float fx = (float)(x+j);
    float ds = dv[j]*s;
    float p0=(ik0*fx+a0)*ds, p1=(ik3*fx+a1)*ds, p2=(ik6*fx+a2)*ds;
    bool filt = (lab[j]==10.0f) || (lab[j]==19.0f);
    depo[j] = filt ? 0.0f : ds;
    cam[p+j] = make_float4(p0, p1, p2, lab[j]);
  }
  ((float4*)out)[i4]      = make_float4(lab[0], lab[1], lab[2], lab[3]);
  ((float4*)(out+HW))[i4] = make_float4(depo[0], depo[1], depo[2], depo[3]);
}

extern "C" void kernel_launch(void* const* d_in, const int* in_sizes, int n_in,
                              void* d_out, int out_size, void* d_ws, size_t ws_size,
                              hipStream_t stream){
  const int*   sem   = (const int*)d_in[0];
  const float* heat  = (const float*)d_in[1];
  const float* off   = (const float*)d_in[2];
  const float* depth = (const float*)d_in[3];
  const float* invK  = (const float*)d_in[4];
  const float* rch   = (const float*)d_in[5];
  float* out = (float*)d_out;

  unsigned* cheight = (unsigned*)d_ws;                                   // 2048*1024*4 = 8MB
  u64* cand = (u64*)((char*)d_ws + (size_t)HW*4);                        // 2048*CREG*8 = 256KB
  Scratch* sc = (Scratch*)((char*)d_ws + (size_t)HW*4 + (size_t)2048*CREG*8);

  const int grid4 = HW/4/256;   // 2048

  k_init<<<1, 1024, 0, stream>>>(sc);
  kA<<<grid4, 256, 0, stream>>>(heat, sem, depth, invK, cand, cheight, sc);
  k_select<<<1, 1024, 0, stream>>>(cand, sc);
  k_h<0><<<64, 256, 0, stream>>>(cheight, sc, rch);
  k_h<1><<<64, 256, 0, stream>>>(cheight, sc, rch);
  k_h<2><<<64, 256, 0, stream>>>(cheight, sc, rch);
  k_final<<<grid4, 256, 0, stream>>>(sem, off, depth, invK, sc, out);
}

// Round 10
// 108.228 us; speedup vs baseline: 1.9472x; 1.1101x over previous
//
#include <hip/hip_runtime.h>
#include <math.h>

#define HH 1024
#define WW 2048
#define HW (HH*WW)
#define KC 32
#define LCAP 6144
#define CREG 16          /* candidate slots per block */
#define SENT 0xFFFFFFFFu
#define BIAS 16777216.0f /* 2^24 */

typedef unsigned long long u64;

struct Scratch {
  unsigned hist[2048];
  unsigned done0, done1, done2;
  int kRemain, nvalid;
  unsigned prefix;
  float scale;
  float ck[KC], m2cy[KC], m2cx[KC];
  unsigned ccnt[2048];   // candidates per kA-block
  unsigned cblk[2048];   // ground heights per kA-block
};

__device__ __forceinline__ unsigned agent_load(const unsigned* p){
  return __hip_atomic_load(p, __ATOMIC_RELAXED, __HIP_MEMORY_SCOPE_AGENT);
}
__device__ __forceinline__ void agent_store(unsigned* p, unsigned v){
  __hip_atomic_store(p, v, __ATOMIC_RELAXED, __HIP_MEMORY_SCOPE_AGENT);
}

// ---- DPP 64-lane u64 max (VALU-speed, no LDS) ----
template<int CTRL>
__device__ __forceinline__ u64 dpp_mov64(u64 x){
  unsigned lo = (unsigned)x, hi = (unsigned)(x>>32);
  unsigned nlo = (unsigned)__builtin_amdgcn_update_dpp((int)lo, (int)lo, CTRL, 0xF, 0xF, false);
  unsigned nhi = (unsigned)__builtin_amdgcn_update_dpp((int)hi, (int)hi, CTRL, 0xF, 0xF, false);
  return ((u64)nhi<<32) | (u64)nlo;
}
__device__ __forceinline__ u64 wave_max64(u64 x){
  u64 y;
  y = dpp_mov64<0x111>(x); if (y > x) x = y;  // row_shr:1
  y = dpp_mov64<0x112>(x); if (y > x) x = y;  // row_shr:2
  y = dpp_mov64<0x114>(x); if (y > x) x = y;  // row_shr:4
  y = dpp_mov64<0x118>(x); if (y > x) x = y;  // row_shr:8
  y = dpp_mov64<0x142>(x); if (y > x) x = y;  // row_bcast:15
  y = dpp_mov64<0x143>(x); if (y > x) x = y;  // row_bcast:31
  unsigned mlo = (unsigned)__builtin_amdgcn_readlane((int)(unsigned)x, 63);
  unsigned mhi = (unsigned)__builtin_amdgcn_readlane((int)(unsigned)(x>>32), 63);
  return ((u64)mhi<<32) | (u64)mlo;
}

#define CSWAP(a,b) { if ((b) > (a)) { u64 _t=(a); (a)=(b); (b)=_t; } }

// 256-thread parallel k-th-bucket selection over sc->hist
template<int PASS>
__device__ void do_pick(Scratch* sc, const float* rch, unsigned* wsum){
  int t = threadIdx.x;
  unsigned v[8];
  #pragma unroll
  for (int j=0;j<8;j++) v[j] = agent_load(&sc->hist[t*8+j]);
  unsigned s = 0;
  #pragma unroll
  for (int j=0;j<8;j++) s += v[j];
  unsigned incl = s;
  #pragma unroll
  for (int d=1; d<64; d<<=1){ unsigned o = __shfl_up(incl, d); if ((t&63) >= d) incl += o; }
  unsigned excl = incl - s;
  if ((t&63)==63) wsum[t>>6] = incl;
  __syncthreads();
  unsigned woff=0, total=0;
  #pragma unroll
  for (int w=0;w<4;w++){ unsigned xw=wsum[w]; if (w < (t>>6)) woff += xw; total += xw; }
  unsigned pre = woff + excl;
  int k;
  if (PASS==0) k = (total>0) ? (int)((total-1)>>1) : 0;
  else         k = sc->kRemain;
  if (total>0 && (unsigned)k >= pre && (unsigned)k < pre + s){
    unsigned kr = (unsigned)k - pre;
    int b_ = 0;
    #pragma unroll
    for (int j=0;j<8;j++){
      if (kr < v[j]){ b_ = t*8+j; break; }
      kr -= v[j];
    }
    sc->kRemain = (int)kr;
    if (PASS==0)      sc->prefix = (unsigned)b_;
    else if (PASS==1) sc->prefix = (sc->prefix << 11) | (unsigned)b_;
    else {
      unsigned key = (sc->prefix << 10) | (unsigned)b_;
      sc->scale = rch[0] / __uint_as_float(key);
    }
  }
  if (PASS==2 && t==0 && total==0) sc->scale = 0.0f;
  if (PASS < 2){
    __syncthreads();
    #pragma unroll
    for (int j=0;j<8;j++) agent_store(&sc->hist[t*8+j], 0u);
  }
}

__global__ __launch_bounds__(1024) void k_init(Scratch* sc){
  int t = threadIdx.x;
  ((uint2*)sc->hist)[t] = make_uint2(0u,0u);
  if (t==0){ sc->done0=0u; sc->done1=0u; sc->done2=0u; }
}

// streaming: candidate + ground compaction into per-block regions (NO global atomics)
__global__ __launch_bounds__(256) void kA(const float* __restrict__ heat,
    const int* __restrict__ sem, const float* __restrict__ depth,
    const float* __restrict__ invK, u64* __restrict__ cand,
    unsigned* __restrict__ cheight, Scratch* __restrict__ sc){
  __shared__ unsigned wc_c[4], wc_g[4];
  int t = threadIdx.x;
  int i4 = blockIdx.x*256 + t;
  int p = i4<<2;
  int y = p>>11, x = p&2047;
  int row = y<<11;

  float4 hq = ((const float4*)heat)[i4];
  int4   s4 = ((const int4*)sem)[i4];
  float4 dc = ((const float4*)depth)[i4];
  float  dl = depth[row + (x>0 ? x-1 : 0)];
  float  dr = depth[row + (x+4<WW ? x+4 : WW-1)];
  int rowu = (y>0)?    row-WW : row;
  int rowd = (y<HH-1)? row+WW : row;
  float4 du = ((const float4*)(depth + rowu))[x>>2];
  float4 dd = ((const float4*)(depth + rowd))[x>>2];
  float ik0=invK[0],ik1=invK[1],ik2=invK[2];
  float ik3=invK[3],ik4=invK[4],ik5=invK[5];
  float ik6=invK[6],ik7=invK[7],ik8=invK[8];

  float hv[4] = {hq.x,hq.y,hq.z,hq.w};
  int   sv[4] = {s4.x,s4.y,s4.z,s4.w};
  float dcv[4]= {dc.x,dc.y,dc.z,dc.w};
  float duv[4]= {du.x,du.y,du.z,du.w};
  float ddv[4]= {dd.x,dd.y,dd.z,dd.w};

  unsigned npos = 0, ng = 0;
  #pragma unroll
  for (int j=0;j<4;j++){ npos += (hv[j] > 0.0f) ? 1u : 0u; ng += (sv[j]==0) ? 1u : 0u; }
  unsigned incc = npos, incg = ng;
  #pragma unroll
  for (int d=1; d<64; d<<=1){
    unsigned oc = __shfl_up(incc, d), og = __shfl_up(incg, d);
    if ((t&63) >= d){ incc += oc; incg += og; }
  }
  if ((t&63)==63){ wc_c[t>>6] = incc; wc_g[t>>6] = incg; }

  float fy = (float)y;
  float a0=ik1*fy+ik2, a1=ik4*fy+ik5, a2=ik7*fy+ik8;
  float fyu=(y>0)?    fy-1.0f : fy;
  float fyd=(y<HH-1)? fy+1.0f : fy;
  float uu0=ik1*fyu+ik2, uu1=ik4*fyu+ik5, uu2=ik7*fyu+ik8;
  float ww0=ik1*fyd+ik2, ww1=ik4*fyd+ik5, ww2=ik7*fyd+ik8;
  float dxmv[4] = {dl, dcv[0], dcv[1], dcv[2]};
  float dxpv[4] = {dcv[1], dcv[2], dcv[3], dr};
  float h[4];
  #pragma unroll
  for (int j=0;j<4;j++){
    float fx  = (float)(x+j);
    float fxm = (x+j>0)?    fx-1.0f : fx;
    float fxp = (x+j<WW-1)? fx+1.0f : fx;
    float pc0=(ik0*fx +a0)*dcv[j],  pc1=(ik3*fx +a1)*dcv[j],  pc2=(ik6*fx +a2)*dcv[j];
    float pm0=(ik0*fxm+a0)*dxmv[j], pm1=(ik3*fxm+a1)*dxmv[j], pm2=(ik6*fxm+a2)*dxmv[j];
    float pp0=(ik0*fxp+a0)*dxpv[j], pp1=(ik3*fxp+a1)*dxpv[j], pp2=(ik6*fxp+a2)*dxpv[j];
    float pu0=(ik0*fx+uu0)*duv[j],  pu1=(ik3*fx+uu1)*duv[j],  pu2=(ik6*fx+uu2)*duv[j];
    float pd0=(ik0*fx+ww0)*ddv[j],  pd1=(ik3*fx+ww1)*ddv[j],  pd2=(ik6*fx+ww2)*ddv[j];
    float vx0=pp0-pm0, vx1=pp1-pm1, vx2=pp2-pm2;
    float vy0=pd0-pu0, vy1=pd1-pu1, vy2=pd2-pu2;
    float n0=vx1*vy2-vx2*vy1, n1=vx2*vy0-vx0*vy2, n2=vx0*vy1-vx1*vy0;
    float nn = sqrtf(n0*n0+n1*n1+n2*n2) + 1e-8f;
    h[j] = fabsf(pc0*n0+pc1*n1+pc2*n2) / nn;
  }

  __syncthreads();
  unsigned cboff=0, gboff=0;
  int myw = t>>6;
  #pragma unroll
  for (int w=0;w<4;w++){
    if (w < myw){ cboff += wc_c[w]; gboff += wc_g[w]; }
  }
  if (npos){
    unsigned cslot = cboff + incc - npos;
    u64* cb = cand + ((size_t)blockIdx.x * CREG);
    #pragma unroll
    for (int j=0;j<4;j++){
      if (hv[j] > 0.0f){
        if (cslot < CREG)
          cb[cslot] = ((u64)__float_as_uint(hv[j])<<32) | (u64)(unsigned)(~(unsigned)(p+j));
        cslot++;
      }
    }
  }
  if (ng){
    unsigned gslot = ((unsigned)blockIdx.x<<10) + gboff + incg - ng;
    #pragma unroll
    for (int j=0;j<4;j++){
      if (sv[j]==0){ cheight[gslot++] = __float_as_uint(h[j]); }
    }
  }
  if (t==0){
    unsigned tc = wc_c[0]+wc_c[1]+wc_c[2]+wc_c[3];
    sc->ccnt[blockIdx.x] = (tc > CREG) ? CREG : tc;
    sc->cblk[blockIdx.x] = wc_g[0]+wc_g[1]+wc_g[2]+wc_g[3];
  }
}

// 1 block, 1024 thr: compact -> per-lane sorted lists -> DPP 64-way merges
__global__ __launch_bounds__(1024) void k_select(const u64* __restrict__ cand, Scratch* sc){
  __shared__ u64 lcache[LCAP];
  __shared__ u64 loc[16*KC];
  __shared__ unsigned stot;
  int t = threadIdx.x;
  int lane = t & 63;
  int w = t >> 6;
  if (t==0) stot = 0u;
  if (t < 16*KC) loc[t] = 0ULL;
  __syncthreads();

  #pragma unroll
  for (int rep=0; rep<2; rep++){
    int r = t + rep*1024;
    unsigned c = sc->ccnt[r];
    if (c){
      unsigned b = atomicAdd(&stot, c);
      const u64* cb = cand + ((size_t)r * CREG);
      for (unsigned i=0;i<c;i++){
        unsigned pos = b+i;
        if (pos < LCAP) lcache[pos] = cb[i];
      }
    }
  }
  __syncthreads();
  int n = (int)stot; if (n > LCAP) n = LCAP;

  // phase 1: per-wave top-32 via per-lane sorted registers + DPP merge
  int chunk = (n + 15) >> 4;           // <= 384
  int start = w * chunk;
  int end   = min(n, start + chunk);
  u64 s0,s1,s2,s3,s4,s5,s6,s7;
  {
    int b0 = start + lane;
    s0 = (b0       < end) ? lcache[b0]       : 0ULL;
    s1 = (b0+64    < end) ? lcache[b0+64]    : 0ULL;
    s2 = (b0+128   < end) ? lcache[b0+128]   : 0ULL;
    s3 = (b0+192   < end) ? lcache[b0+192]   : 0ULL;
    s4 = (b0+256   < end) ? lcache[b0+256]   : 0ULL;
    s5 = (b0+320   < end) ? lcache[b0+320]   : 0ULL;
    s6 = (b0+384   < end) ? lcache[b0+384]   : 0ULL;
    s7 = (b0+448   < end) ? lcache[b0+448]   : 0ULL;
  }
  // Batcher odd-even mergesort, descending (19 comparators)
  CSWAP(s0,s1) CSWAP(s2,s3) CSWAP(s4,s5) CSWAP(s6,s7)
  CSWAP(s0,s2) CSWAP(s1,s3) CSWAP(s4,s6) CSWAP(s5,s7)
  CSWAP(s1,s2) CSWAP(s5,s6)
  CSWAP(s0,s4) CSWAP(s1,s5) CSWAP(s2,s6) CSWAP(s3,s7)
  CSWAP(s2,s4) CSWAP(s3,s5)
  CSWAP(s1,s2) CSWAP(s3,s4) CSWAP(s5,s6)

  u64 key = s0;
  for (int r=0;r<KC;r++){
    u64 m = wave_max64(key);
    if (m == 0ULL) break;
    if (lane == 0) loc[w*KC + r] = m;
    u64 ball = __ballot(key == m);
    int winner = __ffsll((long long)ball) - 1;
    if (lane == winner){
      key = s1; s1=s2; s2=s3; s3=s4; s4=s5; s5=s6; s6=s7; s7=0ULL;
    }
  }
  __syncthreads();

  // phase 2: wave 0 merges 16 sorted lists (cached head keys, DPP max)
  if (w == 0){
    int p2 = 0;
    u64 key2 = (lane < 16) ? loc[lane*KC] : 0ULL;
    int k = 0;
    for (int r=0;r<KC;r++){
      u64 m = wave_max64(key2);
      if (m == 0ULL) break;
      if (lane == 0){
        unsigned idx = ~(unsigned)(m & 0xFFFFFFFFULL);
        float cy = (float)(idx >> 11), cx = (float)(idx & 2047u);
        sc->ck[r]   = cy*cy + cx*cx + BIAS;
        sc->m2cy[r] = -2.0f*cy;
        sc->m2cx[r] = -2.0f*cx;
      }
      u64 ball = __ballot(key2 == m);
      int winner = __ffsll((long long)ball) - 1;
      if (lane == winner){
        p2++;
        key2 = (p2 < KC) ? loc[lane*KC + p2] : 0ULL;
      }
      k = r + 1;
    }
    if (lane == 0) sc->nvalid = k;
  }
}

// histogram over per-block ground regions + ticket-fused pick; grid 64
template<int PASS>
__global__ __launch_bounds__(256) void k_h(const unsigned* __restrict__ ch,
    Scratch* __restrict__ sc, const float* __restrict__ rch){
  __shared__ unsigned hsh[2048];
  __shared__ unsigned cnts[32];
  __shared__ unsigned wsum[4];
  __shared__ int lastf;
  int t = threadIdx.x;
  for (int j=t;j<2048;j+=256) hsh[j]=0u;
  int r0 = blockIdx.x * 32;
  if (t < 32) cnts[t] = sc->cblk[r0+t];
  __syncthreads();
  unsigned pref = sc->prefix;
  for (int r=0;r<32;r++){
    unsigned c = cnts[r];
    const unsigned* base = ch + ((size_t)(r0+r)<<10);
    for (unsigned i=t; i<c; i+=256){
      unsigned key = base[i];
      if (PASS==0)      atomicAdd(&hsh[key>>21], 1u);
      else if (PASS==1){ if ((key>>21) == pref) atomicAdd(&hsh[(key>>10)&2047u], 1u); }
      else             { if ((key>>10) == pref) atomicAdd(&hsh[key & 1023u], 1u); }
    }
  }
  __syncthreads();
  for (int j=t;j<2048;j+=256){ unsigned v=hsh[j]; if (v) atomicAdd(&sc->hist[j], v); }
  __syncthreads();
  if (t==0){
    unsigned* dp = (PASS==0)? &sc->done0 : (PASS==1)? &sc->done1 : &sc->done2;
    lastf = (atomicAdd(dp, 1u) == (unsigned)(gridDim.x-1)) ? 1 : 0;
  }
  __syncthreads();
  if (lastf) do_pick<PASS>(sc, rch, wsum);
}

// labels + scaled depth + cam_out; 4 px/thread, grid 2048
__global__ __launch_bounds__(256) void k_final(const int* __restrict__ sem,
    const float* __restrict__ off, const float* __restrict__ depth,
    const float* __restrict__ invK, const Scratch* __restrict__ sc,
    float* __restrict__ out){
  __shared__ float sck[KC], smy[KC], smx[KC];
  __shared__ int snv; __shared__ float ssc;
  int t = threadIdx.x;
  if (t < KC){ sck[t]=sc->ck[t]; smy[t]=sc->m2cy[t]; smx[t]=sc->m2cx[t]; }
  if (t == 0){ snv = sc->nvalid; ssc = sc->scale; }
  __syncthreads();

  int i4 = blockIdx.x*256 + t;
  int p = i4<<2;
  int y = p>>11, x = p&2047;
  int4   s4 = ((const int4*)sem)[i4];
  float4 oy = ((const float4*)off)[i4];
  float4 ox = ((const float4*)(off+HW))[i4];
  float4 dc = ((const float4*)depth)[i4];

  float ik0=invK[0],ik1=invK[1],ik2=invK[2];
  float ik3=invK[3],ik4=invK[4],ik5=invK[5];
  float ik6=invK[6],ik7=invK[7],ik8=invK[8];
  float fy = (float)y;
  float a0=ik1*fy+ik2, a1=ik4*fy+ik5, a2=ik7*fy+ik8;
  int nv = snv; float s = ssc;

  int   sv[4]  = {s4.x,s4.y,s4.z,s4.w};
  float oyv[4] = {oy.x,oy.y,oy.z,oy.w};
  float oxv[4] = {ox.x,ox.y,ox.z,ox.w};
  float dv[4]  = {dc.x,dc.y,dc.z,dc.w};

  float ys[4], xs[4]; unsigned ub[4];
  #pragma unroll
  for (int j=0;j<4;j++){
    ys[j] = fy + oyv[j]; xs[j] = (float)(x+j) + oxv[j]; ub[j] = SENT;
  }
  for (int k=0;k<nv;k++){
    float ckk=sck[k], my=smy[k], mx=smx[k];
    #pragma unroll
    for (int j=0;j<4;j++){
      float tt = fmaf(ys[j], my, ckk);
      tt = fmaf(xs[j], mx, tt);
      unsigned u = (__float_as_uint(tt) & ~31u) | (unsigned)k;
      ub[j] = u < ub[j] ? u : ub[j];
    }
  }
  float lab[4], depo[4];
  float4* cam = (float4*)(out + (size_t)2*HW);
  #pragma unroll
  for (int j=0;j<4;j++){
    int sj = sv[j];
    lab[j] = (sj >= 11 && nv > 0) ? (float)(sj*1000 + (int)(ub[j]&31u) + 1) : (float)sj;
    float fx = (float)(x+j);
    float ds = dv[j]*s;
    float p0=(ik0*fx+a0)*ds, p1=(ik3*fx+a1)*ds, p2=(ik6*fx+a2)*ds;
    bool filt = (lab[j]==10.0f) || (lab[j]==19.0f);
    depo[j] = filt ? 0.0f : ds;
    cam[p+j] = make_float4(p0, p1, p2, lab[j]);
  }
  ((float4*)out)[i4]      = make_float4(lab[0], lab[1], lab[2], lab[3]);
  ((float4*)(out+HW))[i4] = make_float4(depo[0], depo[1], depo[2], depo[3]);
}

extern "C" void kernel_launch(void* const* d_in, const int* in_sizes, int n_in,
                              void* d_out, int out_size, void* d_ws, size_t ws_size,
                              hipStream_t stream){
  const int*   sem   = (const int*)d_in[0];
  const float* heat  = (const float*)d_in[1];
  const float* off   = (const float*)d_in[2];
  const float* depth = (const float*)d_in[3];
  const float* invK  = (const float*)d_in[4];
  const float* rch   = (const float*)d_in[5];
  float* out = (float*)d_out;

  unsigned* cheight = (unsigned*)d_ws;                                   // 2048*1024*4 = 8MB
  u64* cand = (u64*)((char*)d_ws + (size_t)HW*4);                        // 2048*CREG*8 = 256KB
  Scratch* sc = (Scratch*)((char*)d_ws + (size_t)HW*4 + (size_t)2048*CREG*8);

  const int grid4 = HW/4/256;   // 2048

  k_init<<<1, 1024, 0, stream>>>(sc);
  kA<<<grid4, 256, 0, stream>>>(heat, sem, depth, invK, cand, cheight, sc);
  k_select<<<1, 1024, 0, stream>>>(cand, sc);
  k_h<0><<<64, 256, 0, stream>>>(cheight, sc, rch);
  k_h<1><<<64, 256, 0, stream>>>(cheight, sc, rch);
  k_h<2><<<64, 256, 0, stream>>>(cheight, sc, rch);
  k_final<<<grid4, 256, 0, stream>>>(sem, off, depth, invK, sc, out);
}

// Round 11
// 67.573 us; speedup vs baseline: 3.1187x; 1.6017x over previous
//
#include <hip/hip_runtime.h>
#include <math.h>

#define HH 1024
#define WW 2048
#define HW (HH*WW)
#define KC 32
#define LCAP 6144
#define CREG 16          /* candidate slots per kA block */
#define KCAP 12288       /* LDS-cached ground heights per k_med block */
#define SENT 0xFFFFFFFFu
#define BIAS 16777216.0f /* 2^24 */

typedef unsigned long long u64;

struct Scratch {
  unsigned hist0[2048];
  unsigned hist1[2048];
  unsigned hist2[2048];
  unsigned done0;
  int nvalid;
  float scale;
  float ck[KC], m2cy[KC], m2cx[KC];
  unsigned ccnt[2048];   // candidates per kA-block
  unsigned cblk[2048];   // ground heights per kA-block
};

__device__ __forceinline__ unsigned agent_load(const unsigned* p){
  return __hip_atomic_load(p, __ATOMIC_RELAXED, __HIP_MEMORY_SCOPE_AGENT);
}

// ---- DPP 64-lane u64 max (VALU-speed, no LDS) ----
template<int CTRL>
__device__ __forceinline__ u64 dpp_mov64(u64 x){
  unsigned lo = (unsigned)x, hi = (unsigned)(x>>32);
  unsigned nlo = (unsigned)__builtin_amdgcn_update_dpp((int)lo, (int)lo, CTRL, 0xF, 0xF, false);
  unsigned nhi = (unsigned)__builtin_amdgcn_update_dpp((int)hi, (int)hi, CTRL, 0xF, 0xF, false);
  return ((u64)nhi<<32) | (u64)nlo;
}
__device__ __forceinline__ u64 wave_max64(u64 x){
  u64 y;
  y = dpp_mov64<0x111>(x); if (y > x) x = y;
  y = dpp_mov64<0x112>(x); if (y > x) x = y;
  y = dpp_mov64<0x114>(x); if (y > x) x = y;
  y = dpp_mov64<0x118>(x); if (y > x) x = y;
  y = dpp_mov64<0x142>(x); if (y > x) x = y;
  y = dpp_mov64<0x143>(x); if (y > x) x = y;
  unsigned mlo = (unsigned)__builtin_amdgcn_readlane((int)(unsigned)x, 63);
  unsigned mhi = (unsigned)__builtin_amdgcn_readlane((int)(unsigned)(x>>32), 63);
  return ((u64)mhi<<32) | (u64)mlo;
}

// grid barrier for <=64 co-resident blocks (per-BLOCK atomics only)
__device__ __forceinline__ void grid_bar(unsigned* ctr, unsigned target){
  __syncthreads();            // drains this block's vmem (hist atomics) first
  if (threadIdx.x == 0){
    atomicAdd(ctr, 1u);
    while (__hip_atomic_load(ctr, __ATOMIC_RELAXED, __HIP_MEMORY_SCOPE_AGENT) < target)
      __builtin_amdgcn_s_sleep(2);
  }
  __syncthreads();
}

// per-block redundant k-th-bucket pick over a global hist (512 threads, 4 bins/thread)
template<int PASS>
__device__ __forceinline__ void pick512(const unsigned* gh, unsigned* wsumL, unsigned* res){
  int t = threadIdx.x;
  unsigned v0 = agent_load(&gh[t*4+0]);
  unsigned v1 = agent_load(&gh[t*4+1]);
  unsigned v2 = agent_load(&gh[t*4+2]);
  unsigned v3 = agent_load(&gh[t*4+3]);
  int kin_prev = (PASS==0) ? 0 : (int)res[1];   // read BEFORE the sync below
  unsigned s = v0+v1+v2+v3;
  unsigned incl = s;
  #pragma unroll
  for (int d=1; d<64; d<<=1){ unsigned o = __shfl_up(incl, d); if ((t&63) >= d) incl += o; }
  unsigned excl = incl - s;
  if ((t&63)==63) wsumL[t>>6] = incl;
  __syncthreads();
  unsigned woff=0, total=0;
  #pragma unroll
  for (int w=0;w<8;w++){ unsigned xw=wsumL[w]; if (w < (t>>6)) woff += xw; total += xw; }
  unsigned pre = woff + excl;
  int k = (PASS==0) ? ((total>0) ? (int)((total-1)>>1) : 0) : kin_prev;
  if (total>0 && (unsigned)k >= pre && (unsigned)k < pre + s){
    unsigned kr = (unsigned)k - pre;
    int b_ = t*4;
    if (kr >= v0){ kr -= v0; b_++;
      if (kr >= v1){ kr -= v1; b_++;
        if (kr >= v2){ kr -= v2; b_++; } } }
    res[0] = (unsigned)b_; res[1] = kr;
  }
  if (t==0) res[2] = total;
  __syncthreads();
}

// streaming: candidate + ground compaction into per-block regions (NO global atomics)
// 4 px/thread, grid 2048; block 0 also zeroes Scratch control state for this call
__global__ __launch_bounds__(256) void kA(const float* __restrict__ heat,
    const int* __restrict__ sem, const float* __restrict__ depth,
    const float* __restrict__ invK, u64* __restrict__ cand,
    unsigned* __restrict__ cheight, Scratch* __restrict__ sc){
  __shared__ unsigned wc_c[4], wc_g[4];
  int t = threadIdx.x;
  if (blockIdx.x == 0){
    unsigned* hz = sc->hist0;          // hist0/1/2 contiguous
    for (int j=t; j<6144; j+=256) hz[j] = 0u;
    if (t==0) sc->done0 = 0u;
  }
  int i4 = blockIdx.x*256 + t;
  int p = i4<<2;
  int y = p>>11, x = p&2047;
  int row = y<<11;

  float4 hq = ((const float4*)heat)[i4];
  int4   s4 = ((const int4*)sem)[i4];
  float4 dc = ((const float4*)depth)[i4];
  float  dl = depth[row + (x>0 ? x-1 : 0)];
  float  dr = depth[row + (x+4<WW ? x+4 : WW-1)];
  int rowu = (y>0)?    row-WW : row;
  int rowd = (y<HH-1)? row+WW : row;
  float4 du = ((const float4*)(depth + rowu))[x>>2];
  float4 dd = ((const float4*)(depth + rowd))[x>>2];
  float ik0=invK[0],ik1=invK[1],ik2=invK[2];
  float ik3=invK[3],ik4=invK[4],ik5=invK[5];
  float ik6=invK[6],ik7=invK[7],ik8=invK[8];

  float hv[4] = {hq.x,hq.y,hq.z,hq.w};
  int   sv[4] = {s4.x,s4.y,s4.z,s4.w};
  float dcv[4]= {dc.x,dc.y,dc.z,dc.w};
  float duv[4]= {du.x,du.y,du.z,du.w};
  float ddv[4]= {dd.x,dd.y,dd.z,dd.w};

  unsigned npos = 0, ng = 0;
  #pragma unroll
  for (int j=0;j<4;j++){ npos += (hv[j] > 0.0f) ? 1u : 0u; ng += (sv[j]==0) ? 1u : 0u; }
  unsigned incc = npos, incg = ng;
  #pragma unroll
  for (int d=1; d<64; d<<=1){
    unsigned oc = __shfl_up(incc, d), og = __shfl_up(incg, d);
    if ((t&63) >= d){ incc += oc; incg += og; }
  }
  if ((t&63)==63){ wc_c[t>>6] = incc; wc_g[t>>6] = incg; }

  float fy = (float)y;
  float a0=ik1*fy+ik2, a1=ik4*fy+ik5, a2=ik7*fy+ik8;
  float fyu=(y>0)?    fy-1.0f : fy;
  float fyd=(y<HH-1)? fy+1.0f : fy;
  float uu0=ik1*fyu+ik2, uu1=ik4*fyu+ik5, uu2=ik7*fyu+ik8;
  float ww0=ik1*fyd+ik2, ww1=ik4*fyd+ik5, ww2=ik7*fyd+ik8;
  float dxmv[4] = {dl, dcv[0], dcv[1], dcv[2]};
  float dxpv[4] = {dcv[1], dcv[2], dcv[3], dr};
  float h[4];
  #pragma unroll
  for (int j=0;j<4;j++){
    float fx  = (float)(x+j);
    float fxm = (x+j>0)?    fx-1.0f : fx;
    float fxp = (x+j<WW-1)? fx+1.0f : fx;
    float pc0=(ik0*fx +a0)*dcv[j],  pc1=(ik3*fx +a1)*dcv[j],  pc2=(ik6*fx +a2)*dcv[j];
    float pm0=(ik0*fxm+a0)*dxmv[j], pm1=(ik3*fxm+a1)*dxmv[j], pm2=(ik6*fxm+a2)*dxmv[j];
    float pp0=(ik0*fxp+a0)*dxpv[j], pp1=(ik3*fxp+a1)*dxpv[j], pp2=(ik6*fxp+a2)*dxpv[j];
    float pu0=(ik0*fx+uu0)*duv[j],  pu1=(ik3*fx+uu1)*duv[j],  pu2=(ik6*fx+uu2)*duv[j];
    float pd0=(ik0*fx+ww0)*ddv[j],  pd1=(ik3*fx+ww1)*ddv[j],  pd2=(ik6*fx+ww2)*ddv[j];
    float vx0=pp0-pm0, vx1=pp1-pm1, vx2=pp2-pm2;
    float vy0=pd0-pu0, vy1=pd1-pu1, vy2=pd2-pu2;
    float n0=vx1*vy2-vx2*vy1, n1=vx2*vy0-vx0*vy2, n2=vx0*vy1-vx1*vy0;
    float nn = sqrtf(n0*n0+n1*n1+n2*n2) + 1e-8f;
    h[j] = fabsf(pc0*n0+pc1*n1+pc2*n2) / nn;
  }

  __syncthreads();
  unsigned cboff=0, gboff=0;
  int myw = t>>6;
  #pragma unroll
  for (int w=0;w<4;w++){
    if (w < myw){ cboff += wc_c[w]; gboff += wc_g[w]; }
  }
  if (npos){
    unsigned cslot = cboff + incc - npos;
    u64* cb = cand + ((size_t)blockIdx.x * CREG);
    #pragma unroll
    for (int j=0;j<4;j++){
      if (hv[j] > 0.0f){
        if (cslot < CREG)
          cb[cslot] = ((u64)__float_as_uint(hv[j])<<32) | (u64)(unsigned)(~(unsigned)(p+j));
        cslot++;
      }
    }
  }
  if (ng){
    unsigned gslot = ((unsigned)blockIdx.x<<10) + gboff + incg - ng;
    #pragma unroll
    for (int j=0;j<4;j++){
      if (sv[j]==0){ cheight[gslot++] = __float_as_uint(h[j]); }
    }
  }
  if (t==0){
    unsigned tc = wc_c[0]+wc_c[1]+wc_c[2]+wc_c[3];
    sc->ccnt[blockIdx.x] = (tc > CREG) ? CREG : tc;
    sc->cblk[blockIdx.x] = wc_g[0]+wc_g[1]+wc_g[2]+wc_g[3];
  }
}

// fused median (blocks 0..63, grid-barriers) + top-32 selection (block 64)
__global__ __launch_bounds__(512) void k_med(const unsigned* __restrict__ ch,
    const u64* __restrict__ cand, Scratch* __restrict__ sc,
    const float* __restrict__ rch){
  __shared__ union {
    struct { unsigned keys[KCAP]; } med;                  // 48 KB
    struct { u64 lcache[LCAP]; u64 loc[8*KC]; } sel;      // 50 KB
  } u;
  __shared__ unsigned hsh[2048];
  __shared__ unsigned wsumL[8];
  __shared__ unsigned res[3];       // {bucket, kRemain, total}
  __shared__ unsigned cnts[32];
  __shared__ unsigned rstart[32];
  __shared__ unsigned misc[2];      // {ldsn, ovmask}
  __shared__ unsigned stot;
  int t = threadIdx.x;
  int b = blockIdx.x;
  int lane = t & 63;
  int w = t >> 6;

  if (b == 64){
    // ---------- candidate selection ----------
    if (t==0) stot = 0u;
    if (t < 8*KC) u.sel.loc[t] = 0ULL;
    __syncthreads();
    #pragma unroll
    for (int rep=0; rep<4; rep++){
      int r = t + rep*512;
      unsigned c = sc->ccnt[r];
      if (c){
        unsigned bpos = atomicAdd(&stot, c);
        const u64* cb = cand + ((size_t)r * CREG);
        for (unsigned i=0;i<c;i++){
          unsigned pos = bpos+i;
          if (pos < LCAP) u.sel.lcache[pos] = cb[i];
        }
      }
    }
    __syncthreads();
    int n = (int)stot; if (n > LCAP) n = LCAP;
    int chunk = (n + 7) >> 3;
    int start = w * chunk;
    int end   = min(n, start + chunk);
    u64 c0,c1,c2,c3,c4,c5,c6,c7;
    {
      int b0 = start + lane;
      c0 = (b0     < end) ? u.sel.lcache[b0]     : 0ULL;
      c1 = (b0+64  < end) ? u.sel.lcache[b0+64]  : 0ULL;
      c2 = (b0+128 < end) ? u.sel.lcache[b0+128] : 0ULL;
      c3 = (b0+192 < end) ? u.sel.lcache[b0+192] : 0ULL;
      c4 = (b0+256 < end) ? u.sel.lcache[b0+256] : 0ULL;
      c5 = (b0+320 < end) ? u.sel.lcache[b0+320] : 0ULL;
      c6 = (b0+384 < end) ? u.sel.lcache[b0+384] : 0ULL;
      c7 = (b0+448 < end) ? u.sel.lcache[b0+448] : 0ULL;
    }
    bool over = (end - start) > 512;
    u64 prev = ~0ULL;
    for (int r=0;r<KC;r++){
      u64 best = 0ULL;
      if (c0 < prev && c0 > best) best = c0;
      if (c1 < prev && c1 > best) best = c1;
      if (c2 < prev && c2 > best) best = c2;
      if (c3 < prev && c3 > best) best = c3;
      if (c4 < prev && c4 > best) best = c4;
      if (c5 < prev && c5 > best) best = c5;
      if (c6 < prev && c6 > best) best = c6;
      if (c7 < prev && c7 > best) best = c7;
      if (over){
        for (int idx = start + 512 + lane; idx < end; idx += 64){
          u64 kk = u.sel.lcache[idx];
          if (kk < prev && kk > best) best = kk;
        }
      }
      u64 m = wave_max64(best);
      if (m == 0ULL) break;
      if (lane == 0) u.sel.loc[w*KC + r] = m;
      prev = m;
    }
    __syncthreads();
    if (w == 0){
      int p2 = 0;
      u64 key2 = (lane < 8) ? u.sel.loc[lane*KC] : 0ULL;
      int k = 0;
      for (int r=0;r<KC;r++){
        u64 m = wave_max64(key2);
        if (m == 0ULL) break;
        if (lane == 0){
          unsigned idx = ~(unsigned)(m & 0xFFFFFFFFULL);
          float cy = (float)(idx >> 11), cx = (float)(idx & 2047u);
          sc->ck[r]   = cy*cy + cx*cx + BIAS;
          sc->m2cy[r] = -2.0f*cy;
          sc->m2cx[r] = -2.0f*cx;
        }
        u64 ball = __ballot(key2 == m);
        int winner = __ffsll((long long)ball) - 1;
        if (lane == winner){
          p2++;
          key2 = (p2 < KC) ? u.sel.loc[lane*KC + p2] : 0ULL;
        }
        k = r + 1;
      }
      if (lane == 0) sc->nvalid = k;
    }
    return;
  }

  // ---------- median blocks 0..63 ----------
  int r0 = b * 32;
  if (t < 32) cnts[t] = sc->cblk[r0+t];
  if (t == 0){ res[0]=0u; res[1]=0u; res[2]=0u; }
  for (int j=t;j<2048;j+=512) hsh[j]=0u;
  __syncthreads();
  if (t == 0){
    unsigned acc=0, ov=0;
    for (int r=0;r<32;r++){
      unsigned c = cnts[r];
      if (acc + c <= KCAP){ rstart[r] = acc; acc += c; }
      else { rstart[r] = 0xFFFFFFFFu; ov |= (1u<<r); }
    }
    misc[0] = acc; misc[1] = ov;
  }
  __syncthreads();
  unsigned ldsn = misc[0], ovmask = misc[1];
  for (int r=0;r<32;r++){
    unsigned rs = rstart[r];
    if (rs != 0xFFFFFFFFu){
      unsigned c = cnts[r];
      const unsigned* base = ch + ((size_t)(r0+r)<<10);
      for (unsigned i=t; i<c; i+=512) u.med.keys[rs+i] = base[i];
    }
  }
  __syncthreads();

  // ---- pass 0 ----
  for (unsigned i=t; i<ldsn; i+=512) atomicAdd(&hsh[u.med.keys[i]>>21], 1u);
  {
    unsigned ovm = ovmask;
    while (ovm){
      int r = __ffs(ovm)-1; ovm &= ovm-1;
      unsigned c = cnts[r];
      const unsigned* base = ch + ((size_t)(r0+r)<<10);
      for (unsigned i=t; i<c; i+=512) atomicAdd(&hsh[base[i]>>21], 1u);
    }
  }
  __syncthreads();
  for (int j=t;j<2048;j+=512){ unsigned v=hsh[j]; if (v) atomicAdd(&sc->hist0[j], v); }
  grid_bar(&sc->done0, 64);
  pick512<0>(sc->hist0, wsumL, res);
  unsigned tot0 = res[2];
  unsigned pref0 = res[0];
  for (int j=t;j<2048;j+=512) hsh[j]=0u;
  __syncthreads();

  // ---- pass 1 ----
  for (unsigned i=t; i<ldsn; i+=512){
    unsigned key = u.med.keys[i];
    if ((key>>21) == pref0) atomicAdd(&hsh[(key>>10)&2047u], 1u);
  }
  {
    unsigned ovm = ovmask;
    while (ovm){
      int r = __ffs(ovm)-1; ovm &= ovm-1;
      unsigned c = cnts[r];
      const unsigned* base = ch + ((size_t)(r0+r)<<10);
      for (unsigned i=t; i<c; i+=512){
        unsigned key = base[i];
        if ((key>>21) == pref0) atomicAdd(&hsh[(key>>10)&2047u], 1u);
      }
    }
  }
  __syncthreads();
  for (int j=t;j<2048;j+=512){ unsigned v=hsh[j]; if (v) atomicAdd(&sc->hist1[j], v); }
  grid_bar(&sc->done0, 128);
  pick512<1>(sc->hist1, wsumL, res);
  unsigned pref01 = (pref0 << 11) | res[0];
  for (int j=t;j<2048;j+=512) hsh[j]=0u;
  __syncthreads();

  // ---- pass 2 ----
  for (unsigned i=t; i<ldsn; i+=512){
    unsigned key = u.med.keys[i];
    if ((key>>10) == pref01) atomicAdd(&hsh[key & 1023u], 1u);
  }
  {
    unsigned ovm = ovmask;
    while (ovm){
      int r = __ffs(ovm)-1; ovm &= ovm-1;
      unsigned c = cnts[r];
      const unsigned* base = ch + ((size_t)(r0+r)<<10);
      for (unsigned i=t; i<c; i+=512){
        unsigned key = base[i];
        if ((key>>10) == pref01) atomicAdd(&hsh[key & 1023u], 1u);
      }
    }
  }
  __syncthreads();
  for (int j=t;j<2048;j+=512){ unsigned v=hsh[j]; if (v) atomicAdd(&sc->hist2[j], v); }
  grid_bar(&sc->done0, 192);
  pick512<2>(sc->hist2, wsumL, res);
  if (b == 0 && t == 0){
    unsigned key = (pref01 << 10) | res[0];
    sc->scale = (tot0 > 0) ? (rch[0] / __uint_as_float(key)) : 0.0f;
  }
}

// labels + scaled depth + cam_out; 4 px/thread, grid 2048
__global__ __launch_bounds__(256) void k_final(const int* __restrict__ sem,
    const float* __restrict__ off, const float* __restrict__ depth,
    const float* __restrict__ invK, const Scratch* __restrict__ sc,
    float* __restrict__ out){
  __shared__ float sck[KC], smy[KC], smx[KC];
  __shared__ int snv; __shared__ float ssc;
  int t = threadIdx.x;
  if (t < KC){ sck[t]=sc->ck[t]; smy[t]=sc->m2cy[t]; smx[t]=sc->m2cx[t]; }
  if (t == 0){ snv = sc->nvalid; ssc = sc->scale; }
  __syncthreads();

  int i4 = blockIdx.x*256 + t;
  int p = i4<<2;
  int y = p>>11, x = p&2047;
  int4   s4 = ((const int4*)sem)[i4];
  float4 oy = ((const float4*)off)[i4];
  float4 ox = ((const float4*)(off+HW))[i4];
  float4 dc = ((const float4*)depth)[i4];

  float ik0=invK[0],ik1=invK[1],ik2=invK[2];
  float ik3=invK[3],ik4=invK[4],ik5=invK[5];
  float ik6=invK[6],ik7=invK[7],ik8=invK[8];
  float fy = (float)y;
  float a0=ik1*fy+ik2, a1=ik4*fy+ik5, a2=ik7*fy+ik8;
  int nv = snv; float s = ssc;

  int   sv[4]  = {s4.x,s4.y,s4.z,s4.w};
  float oyv[4] = {oy.x,oy.y,oy.z,oy.w};
  float oxv[4] = {ox.x,ox.y,ox.z,ox.w};
  float dv[4]  = {dc.x,dc.y,dc.z,dc.w};

  float ys[4], xs[4]; unsigned ub[4];
  #pragma unroll
  for (int j=0;j<4;j++){
    ys[j] = fy + oyv[j]; xs[j] = (float)(x+j) + oxv[j]; ub[j] = SENT;
  }
  for (int k=0;k<nv;k++){
    float ckk=sck[k], my=smy[k], mx=smx[k];
    #pragma unroll
    for (int j=0;j<4;j++){
      float tt = fmaf(ys[j], my, ckk);
      tt = fmaf(xs[j], mx, tt);
      unsigned uu = (__float_as_uint(tt) & ~31u) | (unsigned)k;
      ub[j] = uu < ub[j] ? uu : ub[j];
    }
  }
  float lab[4], depo[4];
  float4* cam = (float4*)(out + (size_t)2*HW);
  #pragma unroll
  for (int j=0;j<4;j++){
    int sj = sv[j];
    lab[j] = (sj >= 11 && nv > 0) ? (float)(sj*1000 + (int)(ub[j]&31u) + 1) : (float)sj;
    float fx = (float)(x+j);
    float ds = dv[j]*s;
    float p0=(ik0*fx+a0)*ds, p1=(ik3*fx+a1)*ds, p2=(ik6*fx+a2)*ds;
    bool filt = (lab[j]==10.0f) || (lab[j]==19.0f);
    depo[j] = filt ? 0.0f : ds;
    cam[p+j] = make_float4(p0, p1, p2, lab[j]);
  }
  ((float4*)out)[i4]      = make_float4(lab[0], lab[1], lab[2], lab[3]);
  ((float4*)(out+HW))[i4] = make_float4(depo[0], depo[1], depo[2], depo[3]);
}

extern "C" void kernel_launch(void* const* d_in, const int* in_sizes, int n_in,
                              void* d_out, int out_size, void* d_ws, size_t ws_size,
                              hipStream_t stream){
  const int*   sem   = (const int*)d_in[0];
  const float* heat  = (const float*)d_in[1];
  const float* off   = (const float*)d_in[2];
  const float* depth = (const float*)d_in[3];
  const float* invK  = (const float*)d_in[4];
  const float* rch   = (const float*)d_in[5];
  float* out = (float*)d_out;

  unsigned* cheight = (unsigned*)d_ws;                                   // 2048*1024*4 = 8MB
  u64* cand = (u64*)((char*)d_ws + (size_t)HW*4);                        // 2048*CREG*8 = 256KB
  Scratch* sc = (Scratch*)((char*)d_ws + (size_t)HW*4 + (size_t)2048*CREG*8);

  const int grid4 = HW/4/256;   // 2048

  kA<<<grid4, 256, 0, stream>>>(heat, sem, depth, invK, cand, cheight, sc);
  k_med<<<65, 512, 0, stream>>>(cheight, cand, sc, rch);
  k_final<<<grid4, 256, 0, stream>>>(sem, off, depth, invK, sc, out);
}